// Round 1
// baseline (2327.180 us; speedup 1.0000x reference)
//
#include <hip/hip_runtime.h>
#include <hip/hip_bf16.h>
#include <math.h>

// Problem: fused QKV(+bias) -> RoPE -> 4-head causal attention -> FC2(+bias) -> SiLU
// B=2048, L=119, D=128, H=4, HD=32.  All fp32 in/out; RoPE tables bf16-rounded (as in ref).
// Head split: model channel c = d*4 + h  (reshape(l, HD, NH)).
// Head merge: output channel c' = h*32 + d (transpose then reshape) -- NOT the inverse.
//
// Round 0 design (correctness-first fp32 baseline):
//   K0: RoPE cos/sin tables (bf16 round-trip) into d_ws (61 KB).
//   K1: per-(b,h) block, 256 thr: stage W head-slice (96x128) + x chunks in LDS,
//       fp32 dot -> q,k,v tiles in LDS (v stored transposed), RoPE pass,
//       wave-parallel causal softmax (k cached in regs, shfl reductions),
//       PV with zero-padded p row; y written to d_out in merged layout.
//   K2: FC2 + bias + SiLU in-place on d_out (block owns its 64 rows).

#define L_SEQ 119
#define D_MODEL 128
#define N_HEADS 4
#define HEAD_DIM 32
#define SCALE 0.17677669529663687f  // 1/sqrt(32)

__global__ void rope_tab_kernel(float2* __restrict__ tab) {
  int i = blockIdx.x * blockDim.x + threadIdx.x;
  if (i >= L_SEQ * 64) return;
  int l = i >> 6, j = i & 63;
  float inv = 1.0f / powf(10000.0f, (float)(2 * j) / 128.0f);
  float f = (float)l * inv;
  float c = cosf(f), s = sinf(f);
  tab[i] = make_float2(__bfloat162float(__float2bfloat16(c)),
                       __bfloat162float(__float2bfloat16(s)));
}

// LDS pads: Wl 132 (b128 reads, 4-way), qs/ks 34 (b64 reads, 2-way=free),
// vsT 134 (b64, 2-way=free), xl unpadded (reads are 2-addr broadcast).
__global__ __launch_bounds__(256) void fused_qkv_attn(
    const float* __restrict__ x, const float* __restrict__ Wqkv,
    const float* __restrict__ bqkv, const float2* __restrict__ tab,
    float* __restrict__ out) {
  __shared__ __align__(16) float Wl[96 * 132];   // 50688 B
  __shared__ float bl[96];
  __shared__ __align__(16) float xl[64 * 128];   // 32768 B
  __shared__ __align__(16) float qs[119 * 34];   // 16184 B
  __shared__ __align__(16) float ks[119 * 34];   // 16184 B
  __shared__ __align__(16) float vsT[32 * 134];  // 17152 B (v transposed)
  __shared__ __align__(16) float pl[4 * 128];    // per-wave softmax row

  const int t = threadIdx.x;
  const int b = blockIdx.x >> 2, h = blockIdx.x & 3;

  // ---- stage W head-slice: LDS row j -> global row (j>>5)*128 + (j&31)*4 + h
#pragma unroll
  for (int u = 0; u < 12; ++u) {
    int fidx = t + 256 * u;  // < 96*32
    int row = fidx >> 5, c4 = fidx & 31;
    int grow = (row >> 5) * 128 + (row & 31) * 4 + h;
    *(float4*)&Wl[row * 132 + c4 * 4] =
        *(const float4*)&Wqkv[grow * 128 + c4 * 4];
  }
  if (t < 96) bl[t] = bqkv[(t >> 5) * 128 + (t & 31) * 4 + h];
  // zero vsT tail cols (PV reads up to col 121 via zero-padded p)
  for (int i = t; i < 32 * 15; i += 256)
    vsT[(i / 15) * 134 + 119 + (i % 15)] = 0.0f;

  // ---- QKV projection: per chunk of 64 rows, TM=8 x TN=3 register tile
  const int jx = t & 31, rg = t >> 5;  // jx: head-dim col, rg: row group
#pragma unroll
  for (int chunk = 0; chunk < 2; ++chunk) {
    const int l0 = chunk * 64;
    const int R = chunk ? (L_SEQ - 64) : 64;
    __syncthreads();
    const float* xsrc = x + ((size_t)b * L_SEQ + l0) * D_MODEL;
#pragma unroll
    for (int u = 0; u < 8; ++u) {
      int fidx = t + 256 * u;
      if (fidx < R * 32)
        *(float4*)&xl[fidx * 4] = *(const float4*)&xsrc[(size_t)fidx * 4];
    }
    __syncthreads();
    float acc[8][3] = {};
    for (int k4 = 0; k4 < 32; ++k4) {
      float4 w0 = *(float4*)&Wl[jx * 132 + k4 * 4];
      float4 w1 = *(float4*)&Wl[(32 + jx) * 132 + k4 * 4];
      float4 w2 = *(float4*)&Wl[(64 + jx) * 132 + k4 * 4];
#pragma unroll
      for (int i = 0; i < 8; ++i) {
        float4 xv = *(float4*)&xl[(rg * 8 + i) * 128 + k4 * 4];
        acc[i][0] += xv.x * w0.x + xv.y * w0.y + xv.z * w0.z + xv.w * w0.w;
        acc[i][1] += xv.x * w1.x + xv.y * w1.y + xv.z * w1.z + xv.w * w1.w;
        acc[i][2] += xv.x * w2.x + xv.y * w2.y + xv.z * w2.z + xv.w * w2.w;
      }
    }
#pragma unroll
    for (int i = 0; i < 8; ++i) {
      int r = rg * 8 + i;
      if (r < R) {
        int l = l0 + r;
        qs[l * 34 + jx] = acc[i][0] + bl[jx];
        ks[l * 34 + jx] = acc[i][1] + bl[32 + jx];
        vsT[jx * 134 + l] = acc[i][2] + bl[64 + jx];
      }
    }
  }
  __syncthreads();

  // ---- RoPE on q,k: head-dim pairs (d, d+16), table idx = 4d+h
  for (int idx = t; idx < L_SEQ * 16 * 2; idx += 256) {
    int pid = idx >> 1;
    int l = pid >> 4, dd = pid & 15;
    float2 cs = tab[l * 64 + 4 * dd + h];
    float* base = (idx & 1) ? ks : qs;
    float v1 = base[l * 34 + dd], v2 = base[l * 34 + dd + 16];
    base[l * 34 + dd] = v1 * cs.x + v2 * cs.y;       // y1 = x1*c + x2*s
    base[l * 34 + dd + 16] = v2 * cs.x - v1 * cs.y;  // y2 = -x1*s + x2*c
  }
  __syncthreads();

  // ---- attention: wave w handles rows l = w, w+4, ...
  const int lane = t & 63, w = t >> 6;
  const int dd = lane & 31, half = lane >> 5;
  const int m1 = lane, m2 = 64 + lane;
  const int m2c = (m2 < L_SEQ) ? m2 : (L_SEQ - 1);  // clamp (masked anyway)
  float2 k1r[16], k2r[16];
#pragma unroll
  for (int u = 0; u < 16; ++u) {
    k1r[u] = *(float2*)&ks[m1 * 34 + 2 * u];
    k2r[u] = *(float2*)&ks[m2c * 34 + 2 * u];
  }
  float* plw = &pl[w * 128];
  for (int l = w; l < L_SEQ; l += 4) {
    float s1 = 0.f, s2 = 0.f;
#pragma unroll
    for (int u = 0; u < 16; ++u) {
      float2 qv = *(float2*)&qs[l * 34 + 2 * u];
      s1 += qv.x * k1r[u].x + qv.y * k1r[u].y;
      s2 += qv.x * k2r[u].x + qv.y * k2r[u].y;
    }
    s1 = (m1 <= l) ? s1 * SCALE : -INFINITY;
    s2 = (m2 <= l) ? s2 * SCALE : -INFINITY;
    float mx = fmaxf(s1, s2);
#pragma unroll
    for (int off = 32; off; off >>= 1) mx = fmaxf(mx, __shfl_xor(mx, off));
    float e1 = expf(s1 - mx), e2 = expf(s2 - mx);  // masked -> exp(-inf)=0
    float sum = e1 + e2;
#pragma unroll
    for (int off = 32; off; off >>= 1) sum += __shfl_xor(sum, off);
    float inv = 1.0f / sum;
    plw[m1] = e1 * inv;  // zero beyond causal bound -> PV needs no masking
    plw[m2] = e2 * inv;
    float acc = 0.f;
    int nb = (l >> 2) + 1;  // 4-blocks covering m in [0, l]
    for (int bb = half; bb < nb; bb += 2) {
      float4 p4 = *(float4*)&plw[4 * bb];
      float2 va = *(float2*)&vsT[dd * 134 + 4 * bb];
      float2 vb = *(float2*)&vsT[dd * 134 + 4 * bb + 2];
      acc += p4.x * va.x + p4.y * va.y + p4.z * vb.x + p4.w * vb.y;
    }
    acc += __shfl_xor(acc, 32);  // combine the two m-halves
    if (half == 0)
      out[((size_t)b * L_SEQ + l) * D_MODEL + h * HEAD_DIM + dd] = acc;
  }
}

// FC2 + bias + SiLU, in-place on d_out. Each block owns rows [r0, r0+64).
__global__ __launch_bounds__(256) void fc2_silu_kernel(
    const float* __restrict__ Wfc2, const float* __restrict__ bfc2,
    float* __restrict__ io) {
  __shared__ __align__(16) float yl[64 * 132];
  __shared__ __align__(16) float wl[64 * 132];
  __shared__ float blc[128];
  const int t = threadIdx.x;
  const size_t r0 = (size_t)blockIdx.x * 64;
#pragma unroll
  for (int u = 0; u < 8; ++u) {
    int fidx = t + 256 * u;
    int row = fidx >> 5, c4 = fidx & 31;
    *(float4*)&yl[row * 132 + c4 * 4] =
        *(const float4*)&io[(r0 + row) * 128 + c4 * 4];
  }
  if (t < 128) blc[t] = bfc2[t];
  const int cg = t & 15, rg = t >> 4;
#pragma unroll
  for (int chunk = 0; chunk < 2; ++chunk) {
    __syncthreads();
#pragma unroll
    for (int u = 0; u < 8; ++u) {
      int fidx = t + 256 * u;
      int row = fidx >> 5, c4 = fidx & 31;
      *(float4*)&wl[row * 132 + c4 * 4] =
          *(const float4*)&Wfc2[(chunk * 64 + row) * 128 + c4 * 4];
    }
    __syncthreads();
    float acc[4][4] = {};
    for (int k4 = 0; k4 < 32; ++k4) {
      float4 yv[4], wv[4];
#pragma unroll
      for (int i = 0; i < 4; ++i)
        yv[i] = *(float4*)&yl[(rg + 16 * i) * 132 + k4 * 4];
#pragma unroll
      for (int j = 0; j < 4; ++j)
        wv[j] = *(float4*)&wl[(cg + 16 * j) * 132 + k4 * 4];
#pragma unroll
      for (int i = 0; i < 4; ++i)
#pragma unroll
        for (int j = 0; j < 4; ++j)
          acc[i][j] += yv[i].x * wv[j].x + yv[i].y * wv[j].y +
                       yv[i].z * wv[j].z + yv[i].w * wv[j].w;
    }
#pragma unroll
    for (int i = 0; i < 4; ++i)
#pragma unroll
      for (int j = 0; j < 4; ++j) {
        int r = rg + 16 * i, c = chunk * 64 + cg + 16 * j;
        float v = acc[i][j] + blc[c];
        io[(r0 + r) * 128 + c] = v / (1.0f + expf(-v));  // silu
      }
  }
}

extern "C" void kernel_launch(void* const* d_in, const int* in_sizes, int n_in,
                              void* d_out, int out_size, void* d_ws,
                              size_t ws_size, hipStream_t stream) {
  const float* x = (const float*)d_in[0];
  const float* Wqkv = (const float*)d_in[1];
  const float* bqkv = (const float*)d_in[2];
  const float* Wfc2 = (const float*)d_in[3];
  const float* bfc2 = (const float*)d_in[4];
  float* out = (float*)d_out;
  float2* tab = (float2*)d_ws;  // 119*64 float2 = 60928 B

  const int B = in_sizes[0] / (L_SEQ * D_MODEL);  // 2048
  rope_tab_kernel<<<(L_SEQ * 64 + 255) / 256, 256, 0, stream>>>(tab);
  fused_qkv_attn<<<B * N_HEADS, 256, 0, stream>>>(x, Wqkv, bqkv, tab, out);
  fc2_silu_kernel<<<(B * L_SEQ) / 64, 256, 0, stream>>>(Wfc2, bfc2, out);
}

// Round 2
// 264.162 us; speedup vs baseline: 8.8097x; 8.8097x over previous
//
#include <hip/hip_runtime.h>
#include <hip/hip_bf16.h>
#include <math.h>

// Fused QKV(+bias) -> RoPE -> 4-head causal attention -> FC2(+bias) -> SiLU
// B=2048, L=119, D=128, H=4, HD=32. fp32 in/out, bf16 MFMA internally.
// Head split: model channel c = d*4 + h. Head merge: out channel c' = h*32 + d.
//
// Round 1: bf16 MFMA everywhere.
//  K1 (per batch b, 512 thr = 8 waves, ~125 KB LDS):
//    stage x_b -> bf16 LDS once; per head: stage W_h bf16, QKV via mfma
//    (wave w owns M-tile w, 6 N-tiles), bias+RoPE applied in-register on
//    accumulators, q/k/vT written bf16; attention: QK^T mfma (8 N-tiles),
//    in-register causal softmax (shfl over 16-lane col group), P bf16 strip
//    per wave, PV mfma, fp32 store to d_out (merged layout).
//  K2: FC2+SiLU via mfma, in-place on d_out, 128-row blocks.
// MFMA 16x16x32_bf16 mappings: A/B: lane&15 = row(m)/col(n), k = (lane>>4)*8+j
// (contiguous 8 bf16 = 1 ds_read_b128 from row-major MxK / NxK).
// C/D: col = lane&15, row = (lane>>4)*4 + reg  [m89-verified].
// LDS pads: 136 elems (272 B) or 40 elems (80 B) -> bank advance 4/row -> 2-way (free).

#define L_SEQ 119
#define D_MODEL 128
#define SCALE 0.17677669529663687f  // 1/sqrt(32)
#define NEGINF -1e30f

typedef __bf16 bf16x8 __attribute__((ext_vector_type(8)));
typedef float f32x4 __attribute__((ext_vector_type(4)));

__global__ void rope_tab_kernel(float2* __restrict__ tab) {
  int i = blockIdx.x * blockDim.x + threadIdx.x;
  if (i >= L_SEQ * 64) return;
  int l = i >> 6, j = i & 63;
  float inv = 1.0f / powf(10000.0f, (float)(2 * j) / 128.0f);
  float f = (float)l * inv;
  float c = cosf(f), s = sinf(f);
  tab[i] = make_float2(__bfloat162float(__float2bfloat16(c)),
                       __bfloat162float(__float2bfloat16(s)));
}

__device__ __forceinline__ void cvt4(__bf16* dst, float4 v) {
  dst[0] = (__bf16)v.x; dst[1] = (__bf16)v.y;
  dst[2] = (__bf16)v.z; dst[3] = (__bf16)v.w;
}

__global__ __launch_bounds__(512) void fused_qkv_attn(
    const float* __restrict__ x, const float* __restrict__ Wqkv,
    const float* __restrict__ bqkv, const float2* __restrict__ tab,
    float* __restrict__ out) {
  __shared__ __align__(16) __bf16 xb[128 * 136];   // 34816 B
  __shared__ __align__(16) __bf16 Wl[96 * 136];    // 26112 B
  __shared__ __align__(16) __bf16 qsm[128 * 40];   // 10240 B
  __shared__ __align__(16) __bf16 ksm[128 * 40];   // 10240 B
  __shared__ __align__(16) __bf16 vT[32 * 136];    // 8704 B
  __shared__ __align__(16) __bf16 Ps[128 * 136];   // 34816 B (8 waves x 16-row strip)
  __shared__ float bl[96];

  const int t = threadIdx.x;
  const int b = blockIdx.x;
  const int lane = t & 63, wv = t >> 6;
  const int ln15 = lane & 15, kg = lane >> 4;
  const int mt = wv;  // wave's M-tile (rows mt*16 .. mt*16+15)

  // ---- stage x_b -> bf16 (once, reused by all 4 heads)
  const float* xsrc = x + (size_t)b * L_SEQ * D_MODEL;
  for (int i = t; i < L_SEQ * 32; i += 512) {
    int row = i >> 5, c4 = i & 31;
    cvt4(&xb[row * 136 + c4 * 4], *(const float4*)&xsrc[(size_t)row * 128 + c4 * 4]);
  }
  for (int i = t; i < 9 * 136; i += 512) xb[119 * 136 + i] = (__bf16)0.0f;  // pad rows

  for (int h = 0; h < 4; ++h) {
    __syncthreads();  // xb ready (h=0); guard Wl/q/k/vT overwrite (h>0)
    // ---- stage W head-slice (96 rows: q0-31,k0-31,v0-31 of head h)
    for (int i = t; i < 96 * 32; i += 512) {
      int row = i >> 5, c4 = i & 31;
      int grow = (row >> 5) * 128 + (row & 31) * 4 + h;
      cvt4(&Wl[row * 136 + c4 * 4], *(const float4*)&Wqkv[(size_t)grow * 128 + c4 * 4]);
    }
    if (t < 96) bl[t] = bqkv[(t >> 5) * 128 + (t & 31) * 4 + h];
    __syncthreads();

    // ---- QKV: C[119x96] = xb[119x128] @ Wl^T ; wave -> M-tile mt, 6 N-tiles
    f32x4 acc[6] = {};
    bf16x8 af[4];
#pragma unroll
    for (int kb = 0; kb < 4; ++kb)
      af[kb] = *(const bf16x8*)&xb[(mt * 16 + ln15) * 136 + kb * 32 + kg * 8];
#pragma unroll
    for (int nt = 0; nt < 6; ++nt)
#pragma unroll
      for (int kb = 0; kb < 4; ++kb)
        acc[nt] = __builtin_amdgcn_mfma_f32_16x16x32_bf16(
            af[kb], *(const bf16x8*)&Wl[(nt * 16 + ln15) * 136 + kb * 32 + kg * 8],
            acc[nt], 0, 0, 0);

    // ---- epilogue: bias + in-register RoPE, write q/k (bf16) and v^T (bf16)
#pragma unroll
    for (int r = 0; r < 4; ++r) {
      int l = mt * 16 + kg * 4 + r;
      int lc = (l < L_SEQ) ? l : (L_SEQ - 1);  // clamp for pad rows (values unused)
      float2 cs = tab[lc * 64 + 4 * ln15 + h];
      float q1 = acc[0][r] + bl[ln15], q2 = acc[1][r] + bl[16 + ln15];
      qsm[l * 40 + ln15]      = (__bf16)(q1 * cs.x + q2 * cs.y);
      qsm[l * 40 + 16 + ln15] = (__bf16)(q2 * cs.x - q1 * cs.y);
      float k1 = acc[2][r] + bl[32 + ln15], k2 = acc[3][r] + bl[48 + ln15];
      ksm[l * 40 + ln15]      = (__bf16)(k1 * cs.x + k2 * cs.y);
      ksm[l * 40 + 16 + ln15] = (__bf16)(k2 * cs.x - k1 * cs.y);
      vT[ln15 * 136 + l]        = (__bf16)(acc[4][r] + bl[64 + ln15]);
      vT[(16 + ln15) * 136 + l] = (__bf16)(acc[5][r] + bl[80 + ln15]);
    }
    __syncthreads();

    // ---- attention: S = q k^T (K=32, one mfma per N-tile)
    bf16x8 qf = *(const bf16x8*)&qsm[(mt * 16 + ln15) * 40 + kg * 8];
    f32x4 s[8];
#pragma unroll
    for (int nt = 0; nt < 8; ++nt) {
      f32x4 z = {};
      s[nt] = __builtin_amdgcn_mfma_f32_16x16x32_bf16(
          qf, *(const bf16x8*)&ksm[(nt * 16 + ln15) * 40 + kg * 8], z, 0, 0, 0);
    }
    // causal mask + scale; softmax per row (row spread over 16 lanes x 8 tiles)
    __bf16* Pw = &Ps[wv * 16 * 136];
#pragma unroll
    for (int r = 0; r < 4; ++r) {
      int l = mt * 16 + kg * 4 + r;
      float v[8], mx = NEGINF;
#pragma unroll
      for (int nt = 0; nt < 8; ++nt) {
        int m = nt * 16 + ln15;
        v[nt] = (m <= l) ? s[nt][r] * SCALE : NEGINF;
        mx = fmaxf(mx, v[nt]);
      }
#pragma unroll
      for (int off = 1; off < 16; off <<= 1) mx = fmaxf(mx, __shfl_xor(mx, off));
      float sum = 0.f;
#pragma unroll
      for (int nt = 0; nt < 8; ++nt) { v[nt] = __expf(v[nt] - mx); sum += v[nt]; }
#pragma unroll
      for (int off = 1; off < 16; off <<= 1) sum += __shfl_xor(sum, off);
      float inv = 1.0f / sum;
#pragma unroll
      for (int nt = 0; nt < 8; ++nt)
        Pw[(kg * 4 + r) * 136 + nt * 16 + ln15] = (__bf16)(v[nt] * inv);
    }
    // ---- PV: O[16x32] = P[16x128] @ V[128x32] (vT is V^T, N x K layout)
    f32x4 o[2] = {};
#pragma unroll
    for (int n2 = 0; n2 < 2; ++n2)
#pragma unroll
      for (int kb = 0; kb < 4; ++kb)
        o[n2] = __builtin_amdgcn_mfma_f32_16x16x32_bf16(
            *(const bf16x8*)&Pw[ln15 * 136 + kb * 32 + kg * 8],
            *(const bf16x8*)&vT[(n2 * 16 + ln15) * 136 + kb * 32 + kg * 8],
            o[n2], 0, 0, 0);
#pragma unroll
    for (int n2 = 0; n2 < 2; ++n2)
#pragma unroll
      for (int r = 0; r < 4; ++r) {
        int l = mt * 16 + kg * 4 + r;
        if (l < L_SEQ)
          out[((size_t)b * L_SEQ + l) * 128 + h * 32 + n2 * 16 + ln15] = o[n2][r];
      }
  }
}

// FC2 + bias + SiLU via MFMA, in-place on d_out. Block owns 128 rows.
__global__ __launch_bounds__(256) void fc2_silu_kernel(
    const float* __restrict__ Wfc2, const float* __restrict__ bfc2,
    float* __restrict__ io) {
  __shared__ __align__(16) __bf16 yl[128 * 136];
  __shared__ __align__(16) __bf16 wl[128 * 136];
  __shared__ float blc[128];
  const int t = threadIdx.x;
  const size_t r0 = (size_t)blockIdx.x * 128;
  for (int i = t; i < 128 * 32; i += 256) {
    int row = i >> 5, c4 = i & 31;
    cvt4(&yl[row * 136 + c4 * 4], *(const float4*)&io[(r0 + row) * 128 + c4 * 4]);
    cvt4(&wl[row * 136 + c4 * 4], *(const float4*)&Wfc2[row * 128 + c4 * 4]);
  }
  if (t < 128) blc[t] = bfc2[t];
  __syncthreads();
  const int lane = t & 63, wv = t >> 6;
  const int ln15 = lane & 15, kg = lane >> 4;
#pragma unroll
  for (int mm = 0; mm < 2; ++mm) {
    int mtl = wv * 2 + mm;
    bf16x8 af[4];
#pragma unroll
    for (int kb = 0; kb < 4; ++kb)
      af[kb] = *(const bf16x8*)&yl[(mtl * 16 + ln15) * 136 + kb * 32 + kg * 8];
#pragma unroll
    for (int nt = 0; nt < 8; ++nt) {
      f32x4 acc = {};
#pragma unroll
      for (int kb = 0; kb < 4; ++kb)
        acc = __builtin_amdgcn_mfma_f32_16x16x32_bf16(
            af[kb], *(const bf16x8*)&wl[(nt * 16 + ln15) * 136 + kb * 32 + kg * 8],
            acc, 0, 0, 0);
#pragma unroll
      for (int r = 0; r < 4; ++r) {
        int row = mtl * 16 + kg * 4 + r, c = nt * 16 + ln15;
        float vv = acc[r] + blc[c];
        io[(r0 + row) * 128 + c] = vv / (1.0f + __expf(-vv));
      }
    }
  }
}

extern "C" void kernel_launch(void* const* d_in, const int* in_sizes, int n_in,
                              void* d_out, int out_size, void* d_ws,
                              size_t ws_size, hipStream_t stream) {
  const float* x = (const float*)d_in[0];
  const float* Wqkv = (const float*)d_in[1];
  const float* bqkv = (const float*)d_in[2];
  const float* Wfc2 = (const float*)d_in[3];
  const float* bfc2 = (const float*)d_in[4];
  float* out = (float*)d_out;
  float2* tab = (float2*)d_ws;  // 119*64 float2 = 60928 B

  const int B = in_sizes[0] / (L_SEQ * D_MODEL);  // 2048
  rope_tab_kernel<<<(L_SEQ * 64 + 255) / 256, 256, 0, stream>>>(tab);
  fused_qkv_attn<<<B, 512, 0, stream>>>(x, Wqkv, bqkv, tab, out);
  fc2_silu_kernel<<<(B * L_SEQ) / 128, 256, 0, stream>>>(Wfc2, bfc2, out);
}

// Round 3
// 248.154 us; speedup vs baseline: 9.3780x; 1.0645x over previous
//
#include <hip/hip_runtime.h>
#include <hip/hip_bf16.h>
#include <math.h>

// Fused QKV(+bias) -> RoPE -> 4-head causal attention -> FC2(+bias) -> SiLU
// B=2048, L=119, D=128, H=4, HD=32. fp32 in/out, bf16 MFMA internally.
// Head split: model channel c = d*4 + h. Head merge: out channel c' = h*32 + d.
//
// Round 2: de-serialize the fused kernel.
//  - W_qkv pre-converted to bf16 ONCE (wprep_kernel) into d_ws, laid out in
//    MFMA-B-fragment order (reordered channel n~ = h*96 + qkv*32 + d), so the
//    fused kernel loads B operands straight from global (L2-resident, 1KB/wave
//    coalesced) -- no W LDS, no per-block cvt.
//  - x A-fragments loaded per-wave directly into registers (no xb LDS pass).
//  - QKV for ALL heads in one pass (24 N-tiles), bias+RoPE in-register,
//    ONE barrier, then attention as 32 (h,mt) wave-tasks, no more barriers.
//  LDS: qs/ks [4][128][36], vT [4][32][132], Ps [8][16][132] = 141,312 B.
//  Bank math: stride 36 elem = 18 words -> 16 rows hit 16 distinct banks;
//  stride 132 = 66 words = 2 mod 32 -> 2-way max (free per m136).
// MFMA 16x16x32_bf16: A/B lane&15 = row, k = (lane>>4)*8+j; C/D col=lane&15,
// row=(lane>>4)*4+reg [m89].

#define L_SEQ 119
#define D_MODEL 128
#define SCALE 0.17677669529663687f  // 1/sqrt(32)
#define NEGINF -1e30f

typedef __bf16 bf16x8 __attribute__((ext_vector_type(8)));
typedef float f32x4 __attribute__((ext_vector_type(4)));

__global__ void rope_tab_kernel(float2* __restrict__ tab) {
  int i = blockIdx.x * blockDim.x + threadIdx.x;
  if (i >= L_SEQ * 64) return;
  int l = i >> 6, j = i & 63;
  float inv = 1.0f / powf(10000.0f, (float)(2 * j) / 128.0f);
  float f = (float)l * inv;
  float c = cosf(f), s = sinf(f);
  tab[i] = make_float2(__bfloat162float(__float2bfloat16(c)),
                       __bfloat162float(__float2bfloat16(s)));
}

// Wb fragment layout: flat = ((nt*4 + kb)*64 + lane)*8 + j
//   reordered channel n~ = nt*16 + (lane&15); k = kb*32 + (lane>>4)*8 + j
//   n~ = h*96 + qkv*32 + d  ->  source row = qkv*128 + d*4 + h
__global__ void wprep_kernel(const float* __restrict__ Wqkv,
                             const float* __restrict__ bqkv,
                             __bf16* __restrict__ Wb, float* __restrict__ bb) {
  int i = blockIdx.x * 256 + threadIdx.x;  // 0..49151
  int j = i & 7, lane = (i >> 3) & 63, kb = (i >> 9) & 3, nt = i >> 11;
  int ln15 = lane & 15, kg = lane >> 4;
  int nch = nt * 16 + ln15;
  int h = nch / 96, rem = nch % 96, qkv = rem >> 5, d = rem & 31;
  int srow = qkv * 128 + d * 4 + h;
  int k = kb * 32 + kg * 8 + j;
  Wb[i] = (__bf16)Wqkv[srow * 128 + k];
  if (i < 384) {
    int h2 = i / 96, r2 = i % 96, q2 = r2 >> 5, d2 = r2 & 31;
    bb[i] = bqkv[q2 * 128 + d2 * 4 + h2];
  }
}

__global__ __launch_bounds__(512) void fused_qkv_attn(
    const float* __restrict__ x, const __bf16* __restrict__ Wb,
    const float* __restrict__ bb, const float2* __restrict__ tab,
    float* __restrict__ out) {
  __shared__ __align__(16) __bf16 qs[4 * 128 * 36];   // 36864 B
  __shared__ __align__(16) __bf16 ks[4 * 128 * 36];   // 36864 B
  __shared__ __align__(16) __bf16 vT[4 * 32 * 132];   // 33792 B
  __shared__ __align__(16) __bf16 Ps[8 * 16 * 132];   // 33792 B

  const int t = threadIdx.x, b = blockIdx.x;
  const int lane = t & 63, wv = t >> 6;
  const int ln15 = lane & 15, kg = lane >> 4;
  const int mt = wv;  // wave's QKV M-tile

  // ---- x A-fragments: row mt*16+ln15 (clamped; pad rows discarded later)
  int xr = mt * 16 + ln15;
  if (xr > L_SEQ - 1) xr = L_SEQ - 1;
  const float* xrow = x + ((size_t)b * L_SEQ + xr) * 128;
  bf16x8 af[4];
#pragma unroll
  for (int kb = 0; kb < 4; ++kb) {
    float4 lo = *(const float4*)&xrow[kb * 32 + kg * 8];
    float4 hi = *(const float4*)&xrow[kb * 32 + kg * 8 + 4];
    bf16x8 v;
    v[0] = (__bf16)lo.x; v[1] = (__bf16)lo.y; v[2] = (__bf16)lo.z; v[3] = (__bf16)lo.w;
    v[4] = (__bf16)hi.x; v[5] = (__bf16)hi.y; v[6] = (__bf16)hi.z; v[7] = (__bf16)hi.w;
    af[kb] = v;
  }

  // ---- QKV all heads: 2 passes x 12 N-tiles (keeps acc at 48 VGPRs)
#pragma unroll
  for (int h2 = 0; h2 < 2; ++h2) {
    f32x4 acc[12] = {};
#pragma unroll
    for (int p = 0; p < 12; ++p) {
      int nt = h2 * 12 + p;
#pragma unroll
      for (int kb = 0; kb < 4; ++kb)
        acc[p] = __builtin_amdgcn_mfma_f32_16x16x32_bf16(
            af[kb], *(const bf16x8*)&Wb[(((nt * 4 + kb) * 64) + lane) * 8],
            acc[p], 0, 0, 0);
    }
    // epilogue: bias + RoPE in-register, write q/k and v^T (bf16)
#pragma unroll
    for (int hl = 0; hl < 2; ++hl) {
      int h = h2 * 2 + hl;
      float bias6[6];
#pragma unroll
      for (int p6 = 0; p6 < 6; ++p6)
        bias6[p6] = bb[(h2 * 12 + hl * 6 + p6) * 16 + ln15];
#pragma unroll
      for (int r = 0; r < 4; ++r) {
        int l = mt * 16 + kg * 4 + r;
        int lc = (l < L_SEQ) ? l : (L_SEQ - 1);
        float2 cs = tab[lc * 64 + 4 * ln15 + h];
        float q1 = acc[hl * 6 + 0][r] + bias6[0];
        float q2 = acc[hl * 6 + 1][r] + bias6[1];
        qs[(h * 128 + l) * 36 + ln15]      = (__bf16)(q1 * cs.x + q2 * cs.y);
        qs[(h * 128 + l) * 36 + 16 + ln15] = (__bf16)(q2 * cs.x - q1 * cs.y);
        float k1 = acc[hl * 6 + 2][r] + bias6[2];
        float k2 = acc[hl * 6 + 3][r] + bias6[3];
        ks[(h * 128 + l) * 36 + ln15]      = (__bf16)(k1 * cs.x + k2 * cs.y);
        ks[(h * 128 + l) * 36 + 16 + ln15] = (__bf16)(k2 * cs.x - k1 * cs.y);
        vT[(h * 32 + ln15) * 132 + l]      = (__bf16)(acc[hl * 6 + 4][r] + bias6[4]);
        vT[(h * 32 + 16 + ln15) * 132 + l] = (__bf16)(acc[hl * 6 + 5][r] + bias6[5]);
      }
    }
  }
  __syncthreads();  // the ONLY barrier

  // ---- attention: 32 (h, m-tile) tasks over 8 waves, no further barriers
  __bf16* Pw = &Ps[wv * 16 * 132];
  for (int task = wv; task < 32; task += 8) {
    const int h = task >> 3, m2 = task & 7;
    bf16x8 qf = *(const bf16x8*)&qs[(h * 128 + m2 * 16 + ln15) * 36 + kg * 8];
    f32x4 s[8];
#pragma unroll
    for (int nt = 0; nt < 8; ++nt) {
      f32x4 z = {};
      s[nt] = __builtin_amdgcn_mfma_f32_16x16x32_bf16(
          qf, *(const bf16x8*)&ks[(h * 128 + nt * 16 + ln15) * 36 + kg * 8],
          z, 0, 0, 0);
    }
#pragma unroll
    for (int r = 0; r < 4; ++r) {
      int l = m2 * 16 + kg * 4 + r;
      float v[8], mx = NEGINF;
#pragma unroll
      for (int nt = 0; nt < 8; ++nt) {
        int m = nt * 16 + ln15;
        v[nt] = (m <= l) ? s[nt][r] * SCALE : NEGINF;
        mx = fmaxf(mx, v[nt]);
      }
#pragma unroll
      for (int off = 1; off < 16; off <<= 1) mx = fmaxf(mx, __shfl_xor(mx, off));
      float sum = 0.f;
#pragma unroll
      for (int nt = 0; nt < 8; ++nt) { v[nt] = __expf(v[nt] - mx); sum += v[nt]; }
#pragma unroll
      for (int off = 1; off < 16; off <<= 1) sum += __shfl_xor(sum, off);
      float inv = 1.0f / sum;
#pragma unroll
      for (int nt = 0; nt < 8; ++nt)
        Pw[(kg * 4 + r) * 132 + nt * 16 + ln15] = (__bf16)(v[nt] * inv);
    }
    f32x4 o[2] = {};
#pragma unroll
    for (int n2 = 0; n2 < 2; ++n2)
#pragma unroll
      for (int kb = 0; kb < 4; ++kb)
        o[n2] = __builtin_amdgcn_mfma_f32_16x16x32_bf16(
            *(const bf16x8*)&Pw[ln15 * 132 + kb * 32 + kg * 8],
            *(const bf16x8*)&vT[(h * 32 + n2 * 16 + ln15) * 132 + kb * 32 + kg * 8],
            o[n2], 0, 0, 0);
#pragma unroll
    for (int n2 = 0; n2 < 2; ++n2)
#pragma unroll
      for (int r = 0; r < 4; ++r) {
        int l = m2 * 16 + kg * 4 + r;
        if (l < L_SEQ)
          out[((size_t)b * L_SEQ + l) * 128 + h * 32 + n2 * 16 + ln15] = o[n2][r];
      }
  }
}

// FC2 + bias + SiLU via MFMA, in-place on d_out. Block owns 128 rows.
__global__ __launch_bounds__(256) void fc2_silu_kernel(
    const float* __restrict__ Wfc2, const float* __restrict__ bfc2,
    float* __restrict__ io) {
  __shared__ __align__(16) __bf16 yl[128 * 136];
  __shared__ __align__(16) __bf16 wl[128 * 136];
  __shared__ float blc[128];
  const int t = threadIdx.x;
  const size_t r0 = (size_t)blockIdx.x * 128;
  for (int i = t; i < 128 * 32; i += 256) {
    int row = i >> 5, c4 = i & 31;
    float4 a = *(const float4*)&io[(r0 + row) * 128 + c4 * 4];
    float4 w = *(const float4*)&Wfc2[row * 128 + c4 * 4];
    __bf16* yd = &yl[row * 136 + c4 * 4];
    yd[0] = (__bf16)a.x; yd[1] = (__bf16)a.y; yd[2] = (__bf16)a.z; yd[3] = (__bf16)a.w;
    __bf16* wd = &wl[row * 136 + c4 * 4];
    wd[0] = (__bf16)w.x; wd[1] = (__bf16)w.y; wd[2] = (__bf16)w.z; wd[3] = (__bf16)w.w;
  }
  if (t < 128) blc[t] = bfc2[t];
  __syncthreads();
  const int lane = t & 63, wv = t >> 6;
  const int ln15 = lane & 15, kg = lane >> 4;
#pragma unroll
  for (int mm = 0; mm < 2; ++mm) {
    int mtl = wv * 2 + mm;
    bf16x8 af[4];
#pragma unroll
    for (int kb = 0; kb < 4; ++kb)
      af[kb] = *(const bf16x8*)&yl[(mtl * 16 + ln15) * 136 + kb * 32 + kg * 8];
#pragma unroll
    for (int nt = 0; nt < 8; ++nt) {
      f32x4 acc = {};
#pragma unroll
      for (int kb = 0; kb < 4; ++kb)
        acc = __builtin_amdgcn_mfma_f32_16x16x32_bf16(
            af[kb], *(const bf16x8*)&wl[(nt * 16 + ln15) * 136 + kb * 32 + kg * 8],
            acc, 0, 0, 0);
#pragma unroll
      for (int r = 0; r < 4; ++r) {
        int row = mtl * 16 + kg * 4 + r, c = nt * 16 + ln15;
        float vv = acc[r] + blc[c];
        io[(r0 + row) * 128 + c] = vv / (1.0f + __expf(-vv));
      }
    }
  }
}

extern "C" void kernel_launch(void* const* d_in, const int* in_sizes, int n_in,
                              void* d_out, int out_size, void* d_ws,
                              size_t ws_size, hipStream_t stream) {
  const float* x = (const float*)d_in[0];
  const float* Wqkv = (const float*)d_in[1];
  const float* bqkv = (const float*)d_in[2];
  const float* Wfc2 = (const float*)d_in[3];
  const float* bfc2 = (const float*)d_in[4];
  float* out = (float*)d_out;

  char* ws = (char*)d_ws;
  float2* tab = (float2*)ws;                    // 60,928 B
  __bf16* Wb = (__bf16*)(ws + 61440);           // 98,304 B
  float* bb = (float*)(ws + 61440 + 98304);     // 1,536 B  (total 161,280 B)

  const int B = in_sizes[0] / (L_SEQ * D_MODEL);  // 2048
  rope_tab_kernel<<<(L_SEQ * 64 + 255) / 256, 256, 0, stream>>>(tab);
  wprep_kernel<<<192, 256, 0, stream>>>(Wqkv, bqkv, Wb, bb);
  fused_qkv_attn<<<B, 512, 0, stream>>>(x, Wb, bb, tab, out);
  fc2_silu_kernel<<<(B * L_SEQ) / 128, 256, 0, stream>>>(Wfc2, bfc2, out);
}